// Round 2
// baseline (1376.091 us; speedup 1.0000x reference)
//
#include <hip/hip_runtime.h>
#include <hip/hip_cooperative_groups.h>
#include <math.h>

namespace cg = cooperative_groups;

#define P_TOTAL 147456
#define HW 9216
#define CHW (512*9216)

__device__ __forceinline__ unsigned f2key(float f) {
    unsigned u = __float_as_uint(f);
    return (u & 0x80000000u) ? ~u : (u | 0x80000000u);
}

// ---------- K0: pack protos to [c][side*64+k] and init pwork copy ----------
__global__ void k_init(const float* __restrict__ fg, const float* __restrict__ bg,
                       float* __restrict__ protoP, float* __restrict__ pwork) {
    int i = blockIdx.x * 256 + threadIdx.x;   // 0..65535
    int side = i >> 15;
    int r = i & 32767;
    int k = r >> 9;
    int c = r & 511;
    float v = (side ? bg : fg)[k * 512 + c];
    protoP[c * 128 + side * 64 + k] = v;
    pwork[side * 32768 + k * 512 + c] = v;
}

// ---------- K1: fused scoring: both sides, norm2, combine, hist pass 1 ----------
// protos read with wave-uniform addresses -> scalar (SMEM) loads; no LDS.
__global__ __launch_bounds__(256, 2) void k_score_all(const float* __restrict__ F,
                                                      const float* __restrict__ protoP,
                                                      const float* __restrict__ M,
                                                      float* __restrict__ sfg,
                                                      float* __restrict__ sbg,
                                                      float* __restrict__ invn,
                                                      unsigned* __restrict__ hist) {
    const int p = blockIdx.x * 256 + threadIdx.x;
    const int n = p / HW;
    const int hw = p - n * HW;
    const float* Fp = F + (size_t)n * CHW + hw;

    float af[64], ab[64];
#pragma unroll
    for (int k = 0; k < 64; ++k) { af[k] = 0.f; ab[k] = 0.f; }
    float n2 = 0.f;

#pragma unroll 2
    for (int c = 0; c < 512; ++c) {
        float f = Fp[(size_t)c * HW];
        n2 = fmaf(f, f, n2);
        const float* pc = protoP + c * 128;   // block-uniform address -> s_load
#pragma unroll
        for (int k = 0; k < 64; ++k) af[k] = fmaf(f, pc[k], af[k]);
#pragma unroll
        for (int k = 0; k < 64; ++k) ab[k] = fmaf(f, pc[64 + k], ab[k]);
    }
    float mf = af[0], mb = ab[0];
#pragma unroll
    for (int k = 1; k < 64; ++k) { mf = fmaxf(mf, af[k]); mb = fmaxf(mb, ab[k]); }
    float inv = 1.f / fmaxf(sqrtf(n2), 1e-8f);
    float m = fminf(fmaxf(M[p], 0.f), 1.f);
    float sf = (1.f - mf * inv) * m;
    float sb = (1.f - mb * inv) * (1.f - m);
    sfg[p] = sf; sbg[p] = sb; invn[p] = inv;
    atomicAdd(&hist[f2key(sf) >> 16], 1u);
    atomicAdd(&hist[65536 + (f2key(sb) >> 16)], 1u);
}

// ---------- radix pass 2 histogram ----------
__global__ void k_hist2(const float* __restrict__ sfg, const float* __restrict__ sbg,
                        const int* __restrict__ ctrl, unsigned* __restrict__ hist2) {
    int side = blockIdx.y;
    int p = blockIdx.x * 256 + threadIdx.x;
    float s = side ? sbg[p] : sfg[p];
    unsigned key = f2key(s);
    if ((int)(key >> 16) == ctrl[side * 8 + 0])
        atomicAdd(&hist2[side * 65536 + (key & 0xffffu)], 1u);
}

// ---------- scan: find threshold bucket (pass 0) / exact key (pass 1) ----------
__global__ __launch_bounds__(1024) void k_scan(const unsigned* __restrict__ hist,
                                               int* __restrict__ ctrl, int pass) {
    __shared__ unsigned sd[1024];
    int side = blockIdx.x;
    const unsigned* h = hist + side * 65536;
    int t = threadIdx.x;
    unsigned partial = 0;
    for (int j = 0; j < 64; ++j) partial += h[65535 - (t * 64 + j)];
    sd[t] = partial;
    __syncthreads();
    for (int off = 1; off < 1024; off <<= 1) {
        unsigned v = (t >= off) ? sd[t - off] : 0u;
        __syncthreads();
        sd[t] += v;
        __syncthreads();
    }
    unsigned incl = sd[t];
    unsigned excl = incl - partial;
    unsigned target = (pass == 0) ? 256u : (unsigned)ctrl[side * 8 + 1];
    if (excl < target && target <= incl) {
        unsigned cum = excl;
        for (int j = 0; j < 64; ++j) {
            int b = 65535 - (t * 64 + j);
            unsigned c = h[b];
            if (cum + c >= target) {
                if (pass == 0) {
                    ctrl[side * 8 + 0] = b;
                    ctrl[side * 8 + 1] = (int)(target - cum);
                } else {
                    unsigned vkey = ((unsigned)ctrl[side * 8 + 0] << 16) | (unsigned)b;
                    ctrl[side * 8 + 2] = (int)vkey;
                    int n_gt = (int)(256u - (unsigned)ctrl[side * 8 + 1] + cum);
                    ctrl[side * 8 + 3] = n_gt;
                    ctrl[side * 8 + 4] = 256 - n_gt;
                }
                break;
            }
            cum += c;
        }
    }
}

// ---------- collect indices ----------
__global__ void k_collect(const float* __restrict__ sfg, const float* __restrict__ sbg,
                          int* __restrict__ ctrl, int* __restrict__ idx, int* __restrict__ ties) {
    int side = blockIdx.y;
    int p = blockIdx.x * 256 + threadIdx.x;
    float s = side ? sbg[p] : sfg[p];
    unsigned key = f2key(s);
    unsigned vkey = (unsigned)ctrl[side * 8 + 2];
    if (key > vkey) {
        int pos = atomicAdd(&ctrl[side * 8 + 5], 1);
        idx[side * 256 + pos] = p;
    } else if (key == vkey) {
        int pos = atomicAdd(&ctrl[side * 8 + 6], 1);
        if (pos < 512) ties[side * 512 + pos] = p;
    }
}

// ---------- cooperative: finalize + gather + 10x refine + loss + refined ----------
__global__ __launch_bounds__(256) void k_refine_all(const float* __restrict__ F,
                                                    const float* __restrict__ invn,
                                                    const float* __restrict__ fg,
                                                    const float* __restrict__ bg,
                                                    int* __restrict__ ctrl,
                                                    int* __restrict__ idx,
                                                    int* __restrict__ ties,
                                                    float* __restrict__ feats,
                                                    float* __restrict__ pwork,
                                                    float* __restrict__ sums,   // reused as lpart at the end
                                                    float* __restrict__ cnts,
                                                    float* __restrict__ out) {
    cg::grid_group grid = cg::this_grid();
    const int tid = threadIdx.x;
    const int bid = blockIdx.x;
    const int gw = bid * 4 + (tid >> 6);   // 0..511 (128 blocks x 4 waves)
    const int lane = tid & 63;

    // --- Phase A: tie finalize (smallest indices first, matches jax top_k) ---
    if (bid == 0 && tid < 2) {
        int side = tid;
        int n_gt = ctrl[side * 8 + 3];
        int need = ctrl[side * 8 + 4];
        int cnt = ctrl[side * 8 + 6];
        if (cnt > 512) cnt = 512;
        int* tb = ties + side * 512;
        for (int q = 0; q < need; ++q) {
            int mi = q;
            for (int j = q + 1; j < cnt; ++j) if (tb[j] < tb[mi]) mi = j;
            int tmp = tb[q]; tb[q] = tb[mi]; tb[mi] = tmp;
            idx[side * 256 + n_gt + q] = tb[q];
        }
    }
    grid.sync();

    // --- Phase B: gather normalized selected features (wave per row) ---
    {
        int side = gw >> 8, j = gw & 255;
        int p = idx[side * 256 + j];
        float iv = invn[p];
        int n = p / HW, hw = p - n * HW;
        const float* Fp = F + (size_t)n * CHW + hw;
        float* o = feats + (size_t)gw * 512;
#pragma unroll
        for (int i = 0; i < 8; ++i) {
            int c = lane + i * 64;
            o[c] = Fp[(size_t)c * HW] * iv;
        }
    }
    grid.sync();

    // --- Phase C: 10 refinement iterations ---
    for (int it = 0; it < 10; ++it) {
        // assign: wave gw = (side, point); lane = cluster
        {
            int side = gw >> 8;
            const float4* fr = (const float4*)(feats + (size_t)gw * 512);
            const float4* pw = (const float4*)(pwork + (size_t)side * 32768 + (size_t)lane * 512);
            float dot = 0.f;
#pragma unroll 4
            for (int c = 0; c < 128; ++c) {
                float4 a = fr[c], b = pw[c];
                dot = fmaf(a.x, b.x, dot); dot = fmaf(a.y, b.y, dot);
                dot = fmaf(a.z, b.z, dot); dot = fmaf(a.w, b.w, dot);
            }
            float bv = dot; int bi = lane;
#pragma unroll
            for (int mm = 32; mm >= 1; mm >>= 1) {
                float ov = __shfl_xor(bv, mm);
                int oi = __shfl_xor(bi, mm);
                if (ov > bv || (ov == bv && oi < bi)) { bv = ov; bi = oi; }
            }
            if (lane == 0) atomicAdd(&cnts[side * 64 + bi], 1.f);
            const float* frf = feats + (size_t)gw * 512;
            float* srow = sums + (size_t)side * 32768 + (size_t)bi * 512;
#pragma unroll
            for (int i = 0; i < 8; ++i) {
                int c = lane + i * 64;
                atomicAdd(&srow[c], frf[c]);
            }
        }
        grid.sync();
        // update: waves 0..127 handle (side, cluster); zero sums/cnts for next iter
        if (gw < 128) {
            int side = gw >> 6, k = gw & 63;
            float step = (float)(0.1 / (1.0 + 0.5 * (double)it));
            float cnt = cnts[side * 64 + k];
            float* srow = sums + (size_t)side * 32768 + (size_t)k * 512;
            float* prow = pwork + (size_t)side * 32768 + (size_t)k * 512;
            float bl[8]; float n2 = 0.f;
#pragma unroll
            for (int i = 0; i < 8; ++i) {
                int c = lane + i * 64;
                float mean = srow[c] / fmaxf(cnt, 1.f);
                float v = (1.f - step) * prow[c] + step * mean;
                bl[i] = v; n2 = fmaf(v, v, n2);
                srow[c] = 0.f;
            }
#pragma unroll
            for (int mm = 32; mm >= 1; mm >>= 1) n2 += __shfl_xor(n2, mm);
            float inv = 1.f / fmaxf(sqrtf(n2), 1e-8f);
            if (cnt > 0.f) {
#pragma unroll
                for (int i = 0; i < 8; ++i) prow[lane + i * 64] = bl[i] * inv;
            }
            if (lane == 0) cnts[side * 64 + k] = 0.f;
        }
        grid.sync();
    }

    // --- Phase D: loss partials (sums reused as lpart) ---
    float* lpart = sums;
    {
        int half = gw >> 8, j = gw & 255;
        const float4* fr = (const float4*)(feats + (size_t)gw * 512);
        const float4* pf = (const float4*)(pwork + (size_t)lane * 512);
        const float4* pb = (const float4*)(pwork + 32768 + (size_t)lane * 512);
        if (half == 0) {
            float d1 = 0.f, d2 = 0.f;
            for (int c = 0; c < 128; ++c) {
                float4 a = fr[c], x = pf[c], y = pb[c];
                d1 = fmaf(a.x, x.x, d1); d1 = fmaf(a.y, x.y, d1);
                d1 = fmaf(a.z, x.z, d1); d1 = fmaf(a.w, x.w, d1);
                d2 = fmaf(a.x, y.x, d2); d2 = fmaf(a.y, y.y, d2);
                d2 = fmaf(a.z, y.z, d2); d2 = fmaf(a.w, y.w, d2);
            }
            float smax = d1;
            for (int mm = 32; mm >= 1; mm >>= 1) smax = fmaxf(smax, __shfl_xor(smax, mm));
            float a = d1 / 0.07f, b = d2 / 0.07f;
            float m1 = a;
            for (int mm = 32; mm >= 1; mm >>= 1) m1 = fmaxf(m1, __shfl_xor(m1, mm));
            float mbv = b;
            for (int mm = 32; mm >= 1; mm >>= 1) mbv = fmaxf(mbv, __shfl_xor(mbv, mm));
            float md = fmaxf(m1, mbv);
            float sn = expf(a - m1);
            for (int mm = 32; mm >= 1; mm >>= 1) sn += __shfl_xor(sn, mm);
            float sdn = expf(a - md) + expf(b - md);
            for (int mm = 32; mm >= 1; mm >>= 1) sdn += __shfl_xor(sdn, mm);
            float num = m1 + logf(sn);
            float den = md + logf(sdn);
            if (lane == 0) { lpart[j] = smax; lpart[512 + j] = num - den; }
        } else {
            float d1 = 0.f;
            for (int c = 0; c < 128; ++c) {
                float4 a = fr[c], x = pf[c];
                d1 = fmaf(a.x, x.x, d1); d1 = fmaf(a.y, x.y, d1);
                d1 = fmaf(a.z, x.z, d1); d1 = fmaf(a.w, x.w, d1);
            }
            float smax = d1;
            for (int mm = 32; mm >= 1; mm >>= 1) smax = fmaxf(smax, __shfl_xor(smax, mm));
            if (lane == 0) lpart[256 + j] = smax;
        }
    }
    grid.sync();

    // --- Phase E: final loss (block 0) + refined protos (waves 128..255) ---
    if (bid == 0) {
        __shared__ float red[3][4];
        float sp = lpart[tid], sn = lpart[256 + tid], nm = lpart[512 + tid];
        for (int mm = 32; mm >= 1; mm >>= 1) {
            sp += __shfl_xor(sp, mm); sn += __shfl_xor(sn, mm); nm += __shfl_xor(nm, mm);
        }
        int wv = tid >> 6;
        if ((tid & 63) == 0) { red[0][wv] = sp; red[1][wv] = sn; red[2][wv] = nm; }
        __syncthreads();
        if (tid == 0) {
            float SP = 0, SN = 0, NM = 0;
            for (int i = 0; i < 4; ++i) { SP += red[0][i]; SN += red[1][i]; NM += red[2][i]; }
            SP /= 256.f; SN /= 256.f; NM /= 256.f;
            out[0] = fmaxf(0.f, 0.2f + SN - SP) + 0.25f * (-NM);
        }
    }
    if (gw >= 128 && gw < 256) {
        int w2 = gw - 128;
        int side = w2 >> 6, k = w2 & 63;
        const float* proto = (side ? bg : fg) + (size_t)k * 512;
        const float* prow = pwork + (size_t)side * 32768 + (size_t)k * 512;
        float bl[8]; float n2 = 0.f;
#pragma unroll
        for (int i = 0; i < 8; ++i) {
            int c = lane + i * 64;
            float v = 0.7f * proto[c] + 0.3f * prow[c];
            bl[i] = v; n2 = fmaf(v, v, n2);
        }
#pragma unroll
        for (int mm = 32; mm >= 1; mm >>= 1) n2 += __shfl_xor(n2, mm);
        float inv = 1.f / fmaxf(sqrtf(n2), 1e-8f);
        float* o = out + 1 + (size_t)side * 32768 + (size_t)k * 512;
#pragma unroll
        for (int i = 0; i < 8; ++i) o[lane + i * 64] = bl[i] * inv;
    }
}

extern "C" void kernel_launch(void* const* d_in, const int* in_sizes, int n_in,
                              void* d_out, int out_size, void* d_ws, size_t ws_size,
                              hipStream_t stream) {
    const float* fg = (const float*)d_in[0];
    const float* bg = (const float*)d_in[1];
    const float* F  = (const float*)d_in[2];
    const float* M  = (const float*)d_in[3];
    float* out = (float*)d_out;
    char* ws = (char*)d_ws;

    size_t o = 0;
    auto alloc = [&](size_t bytes) { size_t r = o; o += (bytes + 1023) & ~(size_t)1023; return r; };
    // zeroed region (one memset covers it)
    size_t off_hist1 = alloc(2 * 65536 * 4);
    size_t off_hist2 = alloc(2 * 65536 * 4);
    size_t off_ctrl  = alloc(64);
    size_t off_cnts  = alloc(2 * 64 * 4);
    size_t off_sums  = alloc(2 * 64 * 512 * 4);
    size_t zbytes = o;
    size_t off_sfg   = alloc(P_TOTAL * 4);
    size_t off_sbg   = alloc(P_TOTAL * 4);
    size_t off_inv   = alloc(P_TOTAL * 4);
    size_t off_pP    = alloc(512 * 128 * 4);
    size_t off_idx   = alloc(2 * 256 * 4);
    size_t off_ties  = alloc(2 * 512 * 4);
    size_t off_feats = alloc(2 * 256 * 512 * 4);
    size_t off_pwork = alloc(2 * 64 * 512 * 4);

    unsigned* hist1 = (unsigned*)(ws + off_hist1);
    unsigned* hist2 = (unsigned*)(ws + off_hist2);
    int* ctrl   = (int*)(ws + off_ctrl);
    float* cnts = (float*)(ws + off_cnts);
    float* sums = (float*)(ws + off_sums);
    float* sfg  = (float*)(ws + off_sfg);
    float* sbg  = (float*)(ws + off_sbg);
    float* invn = (float*)(ws + off_inv);
    float* pP   = (float*)(ws + off_pP);
    int* idx    = (int*)(ws + off_idx);
    int* ties   = (int*)(ws + off_ties);
    float* feats = (float*)(ws + off_feats);
    float* pwork = (float*)(ws + off_pwork);

    hipMemsetAsync(ws, 0, zbytes, stream);
    k_init<<<256, 256, 0, stream>>>(fg, bg, pP, pwork);
    k_score_all<<<576, 256, 0, stream>>>(F, pP, M, sfg, sbg, invn, hist1);
    k_scan<<<2, 1024, 0, stream>>>(hist1, ctrl, 0);
    k_hist2<<<dim3(576, 2), 256, 0, stream>>>(sfg, sbg, ctrl, hist2);
    k_scan<<<2, 1024, 0, stream>>>(hist2, ctrl, 1);
    k_collect<<<dim3(576, 2), 256, 0, stream>>>(sfg, sbg, ctrl, idx, ties);

    void* args[] = {(void*)&F, (void*)&invn, (void*)&fg, (void*)&bg,
                    (void*)&ctrl, (void*)&idx, (void*)&ties, (void*)&feats,
                    (void*)&pwork, (void*)&sums, (void*)&cnts, (void*)&out};
    hipLaunchCooperativeKernel((const void*)k_refine_all, dim3(128), dim3(256),
                               args, 0, stream);
}